// Round 4
// baseline (895.786 us; speedup 1.0000x reference)
//
#include <hip/hip_runtime.h>
#include <hip/hip_bf16.h>

#define S_LEN 2048
#define DIM   768
#define NHEAD 12
#define HDIM  64
#define NBLK  32
#define BTOK  8192   // B * S
#define DFF_  3072

typedef __attribute__((ext_vector_type(8))) short bf16x8;
typedef __attribute__((ext_vector_type(4))) float f32x4;

__device__ __forceinline__ void glds16(const void* g, void* l) {
  __builtin_amdgcn_global_load_lds(
      (const __attribute__((address_space(1))) void*)g,
      (__attribute__((address_space(3))) void*)l, 16, 0, 0);
}

__device__ __forceinline__ unsigned short bfbits(float f) {
  __hip_bfloat16 t = __float2bfloat16(f);
  return *(unsigned short*)&t;
}

// ---------------- bb_mask normalization (bool-byte or int32 layout) ---------
__global__ void mask_norm_k(const unsigned char* __restrict__ p,
                            unsigned char* __restrict__ out) {
  int i = blockIdx.x * 256 + threadIdx.x;
  if (i < NBLK * NBLK) {
    bool byteLayout = (p[1] != 0);   // m[0][1] always true
    out[i] = byteLayout ? (unsigned char)(p[i] != 0)
                        : (unsigned char)(((const int*)p)[i] != 0);
  }
}

// ---------------- layernorm: f32 in -> bf16 out, one block per row ----------
__device__ __forceinline__ float blockReduceSum256(float v) {
  v += __shfl_down(v, 32); v += __shfl_down(v, 16); v += __shfl_down(v, 8);
  v += __shfl_down(v, 4);  v += __shfl_down(v, 2);  v += __shfl_down(v, 1);
  __shared__ float sm[4];
  int w = threadIdx.x >> 6;
  __syncthreads();
  if ((threadIdx.x & 63) == 0) sm[w] = v;
  __syncthreads();
  return sm[0] + sm[1] + sm[2] + sm[3];
}

__global__ __launch_bounds__(256) void ln_k(const float* __restrict__ x,
                                            const float* __restrict__ g,
                                            const float* __restrict__ b,
                                            __hip_bfloat16* __restrict__ y) {
  size_t row = blockIdx.x;
  const float* xr = x + row * DIM;
  int t = threadIdx.x;
  float v0 = xr[t], v1 = xr[t + 256], v2 = xr[t + 512];
  float tot = blockReduceSum256(v0 + v1 + v2);
  float mu = tot * (1.0f / DIM);
  float d0 = v0 - mu, d1 = v1 - mu, d2 = v2 - mu;
  float var = blockReduceSum256(d0 * d0 + d1 * d1 + d2 * d2) * (1.0f / DIM);
  float rstd = rsqrtf(var + 1e-5f);
  __hip_bfloat16* yr = y + row * DIM;
  yr[t]       = __float2bfloat16(d0 * rstd * g[t]       + b[t]);
  yr[t + 256] = __float2bfloat16(d1 * rstd * g[t + 256] + b[t + 256]);
  yr[t + 512] = __float2bfloat16(d2 * rstd * g[t + 512] + b[t + 512]);
}

// ---------------- elementwise f32 -> bf16 cast ------------------------------
__global__ __launch_bounds__(256) void castbf_k(const float* __restrict__ x,
                                                __hip_bfloat16* __restrict__ y,
                                                int n) {
  int i = (blockIdx.x * 256 + threadIdx.x) * 8;
  if (i < n) {
    float4 v0 = *(const float4*)(x + i);
    float4 v1 = *(const float4*)(x + i + 4);
    union { bf16x8 v; unsigned short u[8]; } pk;
    pk.u[0] = bfbits(v0.x); pk.u[1] = bfbits(v0.y);
    pk.u[2] = bfbits(v0.z); pk.u[3] = bfbits(v0.w);
    pk.u[4] = bfbits(v1.x); pk.u[5] = bfbits(v1.y);
    pk.u[6] = bfbits(v1.z); pk.u[7] = bfbits(v1.w);
    *(bf16x8*)((unsigned short*)y + i) = pk.v;
  }
}

// ---------------- weight transpose+cast: W[R][C] f32 -> Wt[C][R] bf16 -------
__global__ __launch_bounds__(256) void tcast_k(const float* __restrict__ W,
                                               __hip_bfloat16* __restrict__ Wt,
                                               int R, int C) {
  __shared__ float T[64][65];
  int r0 = blockIdx.y * 64, c0 = blockIdx.x * 64;
  int t = threadIdx.x;
  int r = t >> 2, cg = (t & 3) * 16;
  #pragma unroll
  for (int ii = 0; ii < 16; ii += 4) {
    float4 v = *(const float4*)(W + (size_t)(r0 + r) * C + c0 + cg + ii);
    T[r][cg + ii + 0] = v.x; T[r][cg + ii + 1] = v.y;
    T[r][cg + ii + 2] = v.z; T[r][cg + ii + 3] = v.w;
  }
  __syncthreads();
  int oc = t >> 2, og = (t & 3) * 16;
  union { bf16x8 v; unsigned short u[8]; } p0, p1;
  #pragma unroll
  for (int ii = 0; ii < 8; ++ii) p0.u[ii] = bfbits(T[og + ii][oc]);
  #pragma unroll
  for (int ii = 0; ii < 8; ++ii) p1.u[ii] = bfbits(T[og + 8 + ii][oc]);
  unsigned short* dst = (unsigned short*)Wt + (size_t)(c0 + oc) * R + r0 + og;
  *(bf16x8*)dst = p0.v;
  *(bf16x8*)(dst + 8) = p1.v;
}

// ---------------- bf16 MFMA GEMM: C[M,N] = A[M,K] @ Bt[N,K]^T ---------------
// 128x128 tile, BK=64, 4 waves (2x2 of 64x64), XOR-swizzled LDS (T2/rule 21:
// inverse swizzle applied on global source, same swizzle on ds_read).
template<bool BF16OUT, bool HASBIAS, bool HASRES, bool RELU, bool TRANSV>
__global__ __launch_bounds__(256) void mgemm_k(
    const __hip_bfloat16* __restrict__ A,   // [M][K] bf16
    const __hip_bfloat16* __restrict__ Bt,  // [N][K] bf16
    const float* __restrict__ bias,
    const float* __restrict__ resid,        // f32 [M][N]
    void* __restrict__ Cout,
    int M, int N, int K) {
  __shared__ char Asl[128 * 128];   // 128 rows x 64 bf16
  __shared__ char Bsl[128 * 128];
  int tid = threadIdx.x, w = tid >> 6, lane = tid & 63;
  int g = lane >> 4, cc = lane & 15;
  int wr = w >> 1, wc = w & 1;
  int m0 = blockIdx.y * 128, n0 = blockIdx.x * 128;

  f32x4 acc[4][4];
  #pragma unroll
  for (int i = 0; i < 4; ++i)
    #pragma unroll
    for (int j = 0; j < 4; ++j) acc[i][j] = (f32x4){0.f, 0.f, 0.f, 0.f};

  for (int k0 = 0; k0 < K; k0 += 64) {
    __syncthreads();
    #pragma unroll
    for (int ii = 0; ii < 4; ++ii) {
      int chunk = ii * 256 + w * 64 + lane;
      int row = chunk >> 3, hh = chunk & 7;
      int koff = k0 + ((hh ^ (row & 7)) << 3);
      glds16(A  + (size_t)(m0 + row) * K + koff, Asl + (ii * 256 + w * 64) * 16);
      glds16(Bt + (size_t)(n0 + row) * K + koff, Bsl + (ii * 256 + w * 64) * 16);
    }
    __syncthreads();   // compiler drains vmcnt before s_barrier
    bf16x8 a[4][2], b[4][2];
    #pragma unroll
    for (int i = 0; i < 4; ++i)
      #pragma unroll
      for (int s = 0; s < 2; ++s) {
        int row = wr * 64 + i * 16 + cc;
        a[i][s] = *(const bf16x8*)(Asl + row * 128 + (((s * 4 + g) ^ (cc & 7)) << 4));
      }
    #pragma unroll
    for (int j = 0; j < 4; ++j)
      #pragma unroll
      for (int s = 0; s < 2; ++s) {
        int row = wc * 64 + j * 16 + cc;
        b[j][s] = *(const bf16x8*)(Bsl + row * 128 + (((s * 4 + g) ^ (cc & 7)) << 4));
      }
    #pragma unroll
    for (int i = 0; i < 4; ++i)
      #pragma unroll
      for (int j = 0; j < 4; ++j)
        #pragma unroll
        for (int s = 0; s < 2; ++s)
          acc[i][j] = __builtin_amdgcn_mfma_f32_16x16x32_bf16(a[i][s], b[j][s], acc[i][j], 0, 0, 0);
  }
  #pragma unroll
  for (int i = 0; i < 4; ++i)
    #pragma unroll
    for (int j = 0; j < 4; ++j)
      #pragma unroll
      for (int e = 0; e < 4; ++e) {
        int r   = m0 + wr * 64 + i * 16 + g * 4 + e;
        int col = n0 + wc * 64 + j * 16 + cc;
        float v = acc[i][j][e];
        if (HASBIAS) v += bias[col];
        if (HASRES)  v += resid[(size_t)r * N + col];
        if (RELU)    v = fmaxf(v, 0.f);
        if (TRANSV) {
          int bb = r >> 11, s = r & 2047;   // Vt[b][col][s]
          ((__hip_bfloat16*)Cout)[(size_t)bb * DIM * S_LEN + (size_t)col * S_LEN + s] = __float2bfloat16(v);
        } else if (BF16OUT) {
          ((__hip_bfloat16*)Cout)[(size_t)r * N + col] = __float2bfloat16(v);
        } else {
          ((float*)Cout)[(size_t)r * N + col] = v;
        }
      }
}

// ---------------- block-sparse MFMA flash attention, wave-per-strip ---------
// grid (strip16=128, head, batch), 64 thr = ONE wave owning 16 q-rows.
// No barriers: K/V frags loaded per-lane directly from global (L1/L2-cached;
// K[s][d] d-contig for QK^T B-operand, Vt[d][s] s-contig for PV B-operand).
// Only LDS: 2KB per-wave swizzled P round-trip (wave-internal visibility).
template<bool CAUSAL>
__global__ __launch_bounds__(64) void mattn_k(
    const __hip_bfloat16* __restrict__ Qg,   // [B*S][768]
    const __hip_bfloat16* __restrict__ Kg,   // [B*S][768]
    const __hip_bfloat16* __restrict__ Vtg,  // [B][768][2048]
    __hip_bfloat16* __restrict__ O,          // [B*S][768]
    const unsigned char* __restrict__ mask) {
  __shared__ char Ps[2048];
  int strip = blockIdx.x, h = blockIdx.y, b = blockIdx.z;
  int qb = strip >> 2, wq = strip & 3;
  int lane = threadIdx.x;
  int g = lane >> 4, cc = lane & 15;
  const unsigned short* Qp = (const unsigned short*)Qg;
  const unsigned short* Kp = (const unsigned short*)Kg;
  const unsigned short* Vp = (const unsigned short*)Vtg;

  // Q frags: A-operand rows strip*16+cc, k-contig 8 at d=(s*4+g)*8
  bf16x8 aq[2];
  size_t qrow = ((size_t)b * S_LEN + strip * 16 + cc) * DIM + h * HDIM;
  aq[0] = *(const bf16x8*)(Qp + qrow + g * 8);
  aq[1] = *(const bf16x8*)(Qp + qrow + (4 + g) * 8);

  float m_[4], l_[4];
  f32x4 accO[4];
  #pragma unroll
  for (int e = 0; e < 4; ++e) { m_[e] = -3.0e38f; l_[e] = 0.f; }
  #pragma unroll
  for (int j = 0; j < 4; ++j) accO[j] = (f32x4){0.f, 0.f, 0.f, 0.f};

  int kbEnd = CAUSAL ? (qb + 1) : NBLK;
  for (int kb = 0; kb < kbEnd; ++kb) {
    if (!mask[qb * NBLK + kb]) continue;

    // ---- QK^T: B-frags direct from K (rows kb*64+j*16+cc, d-contig) ----
    f32x4 S[4];
    #pragma unroll
    for (int j = 0; j < 4; ++j) S[j] = (f32x4){0.f, 0.f, 0.f, 0.f};
    #pragma unroll
    for (int j = 0; j < 4; ++j) {
      size_t krow = ((size_t)b * S_LEN + kb * 64 + j * 16 + cc) * DIM + h * HDIM;
      bf16x8 bk0 = *(const bf16x8*)(Kp + krow + g * 8);
      bf16x8 bk1 = *(const bf16x8*)(Kp + krow + (4 + g) * 8);
      S[j] = __builtin_amdgcn_mfma_f32_16x16x32_bf16(aq[0], bk0, S[j], 0, 0, 0);
      S[j] = __builtin_amdgcn_mfma_f32_16x16x32_bf16(aq[1], bk1, S[j], 0, 0, 0);
    }

    // ---- online softmax (row q = g*4+e, values across cc-lanes x j) ----
    float p_[4][4];   // [j][e]
    #pragma unroll
    for (int e = 0; e < 4; ++e) {
      float mm = -3.0e38f;
      #pragma unroll
      for (int j = 0; j < 4; ++j) {
        float sv = S[j][e] * 0.125f;
        if (CAUSAL && kb == qb) {
          int ql = wq * 16 + g * 4 + e, kl = j * 16 + cc;
          if (kl > ql) sv = -1e9f;
        }
        p_[j][e] = sv;
        mm = fmaxf(mm, sv);
      }
      mm = fmaxf(mm, __shfl_xor(mm, 1));
      mm = fmaxf(mm, __shfl_xor(mm, 2));
      mm = fmaxf(mm, __shfl_xor(mm, 4));
      mm = fmaxf(mm, __shfl_xor(mm, 8));
      float newm = fmaxf(m_[e], mm);
      float corr = __expf(m_[e] - newm);
      float rs = 0.f;
      #pragma unroll
      for (int j = 0; j < 4; ++j) {
        float p = __expf(p_[j][e] - newm);
        p_[j][e] = p;
        rs += p;
      }
      rs += __shfl_xor(rs, 1); rs += __shfl_xor(rs, 2);
      rs += __shfl_xor(rs, 4); rs += __shfl_xor(rs, 8);
      l_[e] = l_[e] * corr + rs;
      m_[e] = newm;
      #pragma unroll
      for (int j = 0; j < 4; ++j) accO[j][e] *= corr;
      int ql = g * 4 + e;
      #pragma unroll
      for (int j = 0; j < 4; ++j) {
        int kv = j * 16 + cc;
        int byt = ql * 128 + ((((kv >> 3) ^ (ql & 7))) << 4) + ((kv & 7) << 1);
        *(unsigned short*)(Ps + byt) = bfbits(p_[j][e]);
      }
    }

    // ---- PV: A-frags from per-wave P tile, B-frags direct from Vt ----
    #pragma unroll
    for (int s = 0; s < 2; ++s) {
      bf16x8 ap = *(const bf16x8*)(Ps + cc * 128 + (((s * 4 + g) ^ (cc & 7)) << 4));
      #pragma unroll
      for (int j = 0; j < 4; ++j) {
        size_t vrow = ((size_t)b * DIM + h * HDIM + j * 16 + cc) * S_LEN + kb * 64;
        bf16x8 bv = *(const bf16x8*)(Vp + vrow + (s * 4 + g) * 8);
        accO[j] = __builtin_amdgcn_mfma_f32_16x16x32_bf16(ap, bv, accO[j], 0, 0, 0);
      }
    }
  }
  #pragma unroll
  for (int e = 0; e < 4; ++e) {
    float inv = 1.0f / fmaxf(l_[e], 1e-30f);
    int tok = b * S_LEN + strip * 16 + g * 4 + e;
    #pragma unroll
    for (int j = 0; j < 4; ++j)
      O[(size_t)tok * DIM + h * HDIM + j * 16 + cc] = __float2bfloat16(accO[j][e] * inv);
  }
}

extern "C" void kernel_launch(void* const* d_in, const int* in_sizes, int n_in,
                              void* d_out, int out_size, void* d_ws, size_t ws_size,
                              hipStream_t stream) {
  const float* q    = (const float*)d_in[0];
  const float* enc  = (const float*)d_in[1];
  const unsigned char* bbm = (const unsigned char*)d_in[2];
  const float* Wsrc[8] = {(const float*)d_in[3], (const float*)d_in[4],
                          (const float*)d_in[5], (const float*)d_in[6],
                          (const float*)d_in[7], (const float*)d_in[8],
                          (const float*)d_in[9], (const float*)d_in[10]};
  const float* ln_g = (const float*)d_in[11];
  const float* ln_b = (const float*)d_in[12];
  const float* W1   = (const float*)d_in[13];
  const float* b1   = (const float*)d_in[14];
  const float* W2   = (const float*)d_in[15];
  const float* b2   = (const float*)d_in[16];

  char* ws = (char*)d_ws;
  unsigned char* maskn = (unsigned char*)ws;
  const size_t WT1 = (size_t)DIM * DIM * 2;      // 1,179,648
  __hip_bfloat16* Wt[8];
  for (int i = 0; i < 8; ++i) Wt[i] = (__hip_bfloat16*)(ws + 4096 + i * WT1);
  __hip_bfloat16* W1t  = (__hip_bfloat16*)(ws + 9441280);
  __hip_bfloat16* W2t  = (__hip_bfloat16*)(ws + 14159872);
  __hip_bfloat16* Ebf  = (__hip_bfloat16*)(ws + 18878464);
  float*          X    = (float*)         (ws + 31461376);
  __hip_bfloat16* Abf  = (__hip_bfloat16*)(ws + 56627200);
  __hip_bfloat16* Bq   = (__hip_bfloat16*)(ws + 69210112);
  __hip_bfloat16* Bk   = (__hip_bfloat16*)(ws + 81793024);
  __hip_bfloat16* Vt   = (__hip_bfloat16*)(ws + 94375936);
  __hip_bfloat16* Cc   = (__hip_bfloat16*)(ws + 106958848);
  __hip_bfloat16* F    = Bq;   // [8192][3072] aliases Bq..Cc (dead in FFN phase)

  dim3 blk(256);
  dim3 gsq(12, 12), gw1(48, 12), gw2(12, 48);
  dim3 g768(6, 64), gff(24, 64);
  dim3 ga(128, NHEAD, 4);
  dim3 wv(64);

  mask_norm_k<<<4, blk, 0, stream>>>(bbm, maskn);
  for (int i = 0; i < 8; ++i)
    tcast_k<<<gsq, blk, 0, stream>>>(Wsrc[i], Wt[i], DIM, DIM);
  tcast_k<<<gw1, blk, 0, stream>>>(W1, W1t, DIM, DFF_);
  tcast_k<<<gw2, blk, 0, stream>>>(W2, W2t, DFF_, DIM);
  castbf_k<<<3072, blk, 0, stream>>>(enc, Ebf, BTOK * DIM);

  // ---- self attention ----
  ln_k<<<BTOK, blk, 0, stream>>>(q, ln_g, ln_b, Abf);
  mgemm_k<true,false,false,false,false><<<g768, blk, 0, stream>>>(Abf, Wt[0], nullptr, nullptr, Bq, BTOK, DIM, DIM);
  mgemm_k<true,false,false,false,false><<<g768, blk, 0, stream>>>(Abf, Wt[1], nullptr, nullptr, Bk, BTOK, DIM, DIM);
  mgemm_k<true,false,false,false,true ><<<g768, blk, 0, stream>>>(Abf, Wt[2], nullptr, nullptr, Vt, BTOK, DIM, DIM);
  mattn_k<true><<<ga, wv, 0, stream>>>(Bq, Bk, Vt, Cc, maskn);
  mgemm_k<false,false,true,false,false><<<g768, blk, 0, stream>>>(Cc, Wt[3], nullptr, q, X, BTOK, DIM, DIM);

  // ---- cross attention (KV from raw encoder_out) ----
  ln_k<<<BTOK, blk, 0, stream>>>(X, ln_g, ln_b, Abf);
  mgemm_k<true,false,false,false,false><<<g768, blk, 0, stream>>>(Abf, Wt[4], nullptr, nullptr, Bq, BTOK, DIM, DIM);
  mgemm_k<true,false,false,false,false><<<g768, blk, 0, stream>>>(Ebf, Wt[5], nullptr, nullptr, Bk, BTOK, DIM, DIM);
  mgemm_k<true,false,false,false,true ><<<g768, blk, 0, stream>>>(Ebf, Wt[6], nullptr, nullptr, Vt, BTOK, DIM, DIM);
  mattn_k<false><<<ga, wv, 0, stream>>>(Bq, Bk, Vt, Cc, maskn);
  mgemm_k<false,false,true,false,false><<<g768, blk, 0, stream>>>(Cc, Wt[7], nullptr, X, X, BTOK, DIM, DIM);

  // ---- FFN ----
  ln_k<<<BTOK, blk, 0, stream>>>(X, ln_g, ln_b, Abf);
  mgemm_k<true,true,false,true,false><<<gff, blk, 0, stream>>>(Abf, W1t, b1, nullptr, F, BTOK, DFF_, DIM);
  mgemm_k<false,true,true,false,false><<<g768, blk, 0, stream>>>(F, W2t, b2, X, d_out, BTOK, DIM, DFF_);

  (void)in_sizes; (void)n_in; (void)out_size; (void)ws_size;
}

// Round 5
// 864.822 us; speedup vs baseline: 1.0358x; 1.0358x over previous
//
#include <hip/hip_runtime.h>
#include <hip/hip_bf16.h>

#define S_LEN 2048
#define DIM   768
#define NHEAD 12
#define HDIM  64
#define NBLK  32
#define BTOK  8192   // B * S
#define DFF_  3072

typedef __attribute__((ext_vector_type(8))) short bf16x8;
typedef __attribute__((ext_vector_type(4))) float f32x4;

__device__ __forceinline__ void glds16(const void* g, void* l) {
  __builtin_amdgcn_global_load_lds(
      (const __attribute__((address_space(1))) void*)g,
      (__attribute__((address_space(3))) void*)l, 16, 0, 0);
}

__device__ __forceinline__ unsigned short bfbits(float f) {
  __hip_bfloat16 t = __float2bfloat16(f);
  return *(unsigned short*)&t;
}

// ---------------- bb_mask normalization (bool-byte or int32 layout) ---------
__global__ void mask_norm_k(const unsigned char* __restrict__ p,
                            unsigned char* __restrict__ out) {
  int i = blockIdx.x * 256 + threadIdx.x;
  if (i < NBLK * NBLK) {
    bool byteLayout = (p[1] != 0);   // m[0][1] always true
    out[i] = byteLayout ? (unsigned char)(p[i] != 0)
                        : (unsigned char)(((const int*)p)[i] != 0);
  }
}

// ---------------- layernorm: f32 in -> bf16 out, one block per row ----------
__device__ __forceinline__ float blockReduceSum256(float v) {
  v += __shfl_down(v, 32); v += __shfl_down(v, 16); v += __shfl_down(v, 8);
  v += __shfl_down(v, 4);  v += __shfl_down(v, 2);  v += __shfl_down(v, 1);
  __shared__ float sm[4];
  int w = threadIdx.x >> 6;
  __syncthreads();
  if ((threadIdx.x & 63) == 0) sm[w] = v;
  __syncthreads();
  return sm[0] + sm[1] + sm[2] + sm[3];
}

__global__ __launch_bounds__(256) void ln_k(const float* __restrict__ x,
                                            const float* __restrict__ g,
                                            const float* __restrict__ b,
                                            __hip_bfloat16* __restrict__ y) {
  size_t row = blockIdx.x;
  const float* xr = x + row * DIM;
  int t = threadIdx.x;
  float v0 = xr[t], v1 = xr[t + 256], v2 = xr[t + 512];
  float tot = blockReduceSum256(v0 + v1 + v2);
  float mu = tot * (1.0f / DIM);
  float d0 = v0 - mu, d1 = v1 - mu, d2 = v2 - mu;
  float var = blockReduceSum256(d0 * d0 + d1 * d1 + d2 * d2) * (1.0f / DIM);
  float rstd = rsqrtf(var + 1e-5f);
  __hip_bfloat16* yr = y + row * DIM;
  yr[t]       = __float2bfloat16(d0 * rstd * g[t]       + b[t]);
  yr[t + 256] = __float2bfloat16(d1 * rstd * g[t + 256] + b[t + 256]);
  yr[t + 512] = __float2bfloat16(d2 * rstd * g[t + 512] + b[t + 512]);
}

// ---------------- elementwise f32 -> bf16 cast ------------------------------
__global__ __launch_bounds__(256) void castbf_k(const float* __restrict__ x,
                                                __hip_bfloat16* __restrict__ y,
                                                int n) {
  int i = (blockIdx.x * 256 + threadIdx.x) * 8;
  if (i < n) {
    float4 v0 = *(const float4*)(x + i);
    float4 v1 = *(const float4*)(x + i + 4);
    union { bf16x8 v; unsigned short u[8]; } pk;
    pk.u[0] = bfbits(v0.x); pk.u[1] = bfbits(v0.y);
    pk.u[2] = bfbits(v0.z); pk.u[3] = bfbits(v0.w);
    pk.u[4] = bfbits(v1.x); pk.u[5] = bfbits(v1.y);
    pk.u[6] = bfbits(v1.z); pk.u[7] = bfbits(v1.w);
    *(bf16x8*)((unsigned short*)y + i) = pk.v;
  }
}

// ---------------- weight transpose+cast: W[R][C] f32 -> Wt[C][R] bf16 -------
__global__ __launch_bounds__(256) void tcast_k(const float* __restrict__ W,
                                               __hip_bfloat16* __restrict__ Wt,
                                               int R, int C) {
  __shared__ float T[64][65];
  int r0 = blockIdx.y * 64, c0 = blockIdx.x * 64;
  int t = threadIdx.x;
  int r = t >> 2, cg = (t & 3) * 16;
  #pragma unroll
  for (int ii = 0; ii < 16; ii += 4) {
    float4 v = *(const float4*)(W + (size_t)(r0 + r) * C + c0 + cg + ii);
    T[r][cg + ii + 0] = v.x; T[r][cg + ii + 1] = v.y;
    T[r][cg + ii + 2] = v.z; T[r][cg + ii + 3] = v.w;
  }
  __syncthreads();
  int oc = t >> 2, og = (t & 3) * 16;
  union { bf16x8 v; unsigned short u[8]; } p0, p1;
  #pragma unroll
  for (int ii = 0; ii < 8; ++ii) p0.u[ii] = bfbits(T[og + ii][oc]);
  #pragma unroll
  for (int ii = 0; ii < 8; ++ii) p1.u[ii] = bfbits(T[og + 8 + ii][oc]);
  unsigned short* dst = (unsigned short*)Wt + (size_t)(c0 + oc) * R + r0 + og;
  *(bf16x8*)dst = p0.v;
  *(bf16x8*)(dst + 8) = p1.v;
}

// ---------------- bf16 MFMA GEMM: C[M,N] = A[M,K] @ Bt[N,K]^T ---------------
template<bool BF16OUT, bool HASBIAS, bool HASRES, bool RELU, bool TRANSV>
__global__ __launch_bounds__(256) void mgemm_k(
    const __hip_bfloat16* __restrict__ A,   // [M][K] bf16
    const __hip_bfloat16* __restrict__ Bt,  // [N][K] bf16
    const float* __restrict__ bias,
    const float* __restrict__ resid,        // f32 [M][N]
    void* __restrict__ Cout,
    int M, int N, int K) {
  __shared__ char Asl[128 * 128];   // 128 rows x 64 bf16
  __shared__ char Bsl[128 * 128];
  int tid = threadIdx.x, w = tid >> 6, lane = tid & 63;
  int g = lane >> 4, cc = lane & 15;
  int wr = w >> 1, wc = w & 1;
  int m0 = blockIdx.y * 128, n0 = blockIdx.x * 128;

  f32x4 acc[4][4];
  #pragma unroll
  for (int i = 0; i < 4; ++i)
    #pragma unroll
    for (int j = 0; j < 4; ++j) acc[i][j] = (f32x4){0.f, 0.f, 0.f, 0.f};

  for (int k0 = 0; k0 < K; k0 += 64) {
    __syncthreads();
    #pragma unroll
    for (int ii = 0; ii < 4; ++ii) {
      int chunk = ii * 256 + w * 64 + lane;
      int row = chunk >> 3, hh = chunk & 7;
      int koff = k0 + ((hh ^ (row & 7)) << 3);
      glds16(A  + (size_t)(m0 + row) * K + koff, Asl + (ii * 256 + w * 64) * 16);
      glds16(Bt + (size_t)(n0 + row) * K + koff, Bsl + (ii * 256 + w * 64) * 16);
    }
    __syncthreads();
    bf16x8 a[4][2], b[4][2];
    #pragma unroll
    for (int i = 0; i < 4; ++i)
      #pragma unroll
      for (int s = 0; s < 2; ++s) {
        int row = wr * 64 + i * 16 + cc;
        a[i][s] = *(const bf16x8*)(Asl + row * 128 + (((s * 4 + g) ^ (cc & 7)) << 4));
      }
    #pragma unroll
    for (int j = 0; j < 4; ++j)
      #pragma unroll
      for (int s = 0; s < 2; ++s) {
        int row = wc * 64 + j * 16 + cc;
        b[j][s] = *(const bf16x8*)(Bsl + row * 128 + (((s * 4 + g) ^ (cc & 7)) << 4));
      }
    #pragma unroll
    for (int i = 0; i < 4; ++i)
      #pragma unroll
      for (int j = 0; j < 4; ++j)
        #pragma unroll
        for (int s = 0; s < 2; ++s)
          acc[i][j] = __builtin_amdgcn_mfma_f32_16x16x32_bf16(a[i][s], b[j][s], acc[i][j], 0, 0, 0);
  }
  #pragma unroll
  for (int i = 0; i < 4; ++i)
    #pragma unroll
    for (int j = 0; j < 4; ++j)
      #pragma unroll
      for (int e = 0; e < 4; ++e) {
        int r   = m0 + wr * 64 + i * 16 + g * 4 + e;
        int col = n0 + wc * 64 + j * 16 + cc;
        float v = acc[i][j][e];
        if (HASBIAS) v += bias[col];
        if (HASRES)  v += resid[(size_t)r * N + col];
        if (RELU)    v = fmaxf(v, 0.f);
        if (TRANSV) {
          int bb = r >> 11, s = r & 2047;   // Vt[b][col][s]
          ((__hip_bfloat16*)Cout)[(size_t)bb * DIM * S_LEN + (size_t)col * S_LEN + s] = __float2bfloat16(v);
        } else if (BF16OUT) {
          ((__hip_bfloat16*)Cout)[(size_t)r * N + col] = __float2bfloat16(v);
        } else {
          ((float*)Cout)[(size_t)r * N + col] = v;
        }
      }
}

// ---------------- block-sparse MFMA flash attention -------------------------
// Linear grid 1536 wg x 256 thr. XCD-chunked swizzle: slot=(lin&7)*192+lin>>3
// (bijective) -> each XCD owns 6 (b,h) pairs (K+V 512KB each, L2-resident).
// slot -> (pair, qb); 4 waves = 4 q-strips of 16 rows, zero barriers.
// Register software pipeline: prefetch next active block's K+V during
// current block's QK/softmax/PV. Per-wave 2KB swizzled P LDS round-trip.
#define LOADK(kbv, dst)                                                       \
  { _Pragma("unroll")                                                         \
    for (int j = 0; j < 4; ++j) {                                             \
      size_t kro = ((size_t)b * S_LEN + (kbv) * 64 + j * 16 + cc) * DIM       \
                   + h * HDIM + g * 8;                                        \
      dst[j][0] = *(const bf16x8*)(Kp + kro);                                 \
      dst[j][1] = *(const bf16x8*)(Kp + kro + 32);                            \
    } }
#define LOADV(kbv, dst)                                                       \
  { _Pragma("unroll")                                                         \
    for (int j = 0; j < 4; ++j) {                                             \
      size_t vro = ((size_t)b * DIM + h * HDIM + j * 16 + cc) * S_LEN         \
                   + (kbv) * 64 + g * 8;                                      \
      dst[j][0] = *(const bf16x8*)(Vp + vro);                                 \
      dst[j][1] = *(const bf16x8*)(Vp + vro + 32);                            \
    } }

template<bool CAUSAL>
__global__ __launch_bounds__(256) void mattn_k(
    const __hip_bfloat16* __restrict__ Qg,   // [B*S][768]
    const __hip_bfloat16* __restrict__ Kg,   // [B*S][768]
    const __hip_bfloat16* __restrict__ Vtg,  // [B][768][2048]
    __hip_bfloat16* __restrict__ O,          // [B*S][768]
    const unsigned char* __restrict__ mask) {
  __shared__ char Ps[8192];
  int lin = blockIdx.x;
  int slot = (lin & 7) * 192 + (lin >> 3);
  int pair = slot >> 5, qb = slot & 31;
  int h = pair % NHEAD, b = pair / NHEAD;
  int t = threadIdx.x, w = t >> 6, lane = t & 63;
  int g = lane >> 4, cc = lane & 15;
  int strip = qb * 4 + w;
  char* Pw = Ps + w * 2048;
  const unsigned short* Qp = (const unsigned short*)Qg;
  const unsigned short* Kp = (const unsigned short*)Kg;
  const unsigned short* Vp = (const unsigned short*)Vtg;

  bf16x8 aq0, aq1;
  size_t qrow = ((size_t)b * S_LEN + strip * 16 + cc) * DIM + h * HDIM;
  aq0 = *(const bf16x8*)(Qp + qrow + g * 8);
  aq1 = *(const bf16x8*)(Qp + qrow + (4 + g) * 8);

  float m_[4], l_[4];
  f32x4 accO[4];
  #pragma unroll
  for (int e = 0; e < 4; ++e) { m_[e] = -3.0e38f; l_[e] = 0.f; }
  #pragma unroll
  for (int j = 0; j < 4; ++j) accO[j] = (f32x4){0.f, 0.f, 0.f, 0.f};

  const unsigned char* mrow = mask + qb * NBLK;
  int kbEnd = CAUSAL ? (qb + 1) : NBLK;

  int cur = 0;
  while (!mrow[cur]) ++cur;          // col 0 is global: always an active block
  bf16x8 kc[4][2], vc[4][2];
  LOADK(cur, kc); LOADV(cur, vc);

  for (;;) {
    int nxt = cur + 1;
    while (nxt < kbEnd && !mrow[nxt]) ++nxt;
    bool more = (nxt < kbEnd);
    bf16x8 kn[4][2], vn[4][2];
    if (more) { LOADK(nxt, kn); LOADV(nxt, vn); }   // prefetch in flight

    // ---- QK^T on current block ----
    f32x4 S[4];
    #pragma unroll
    for (int j = 0; j < 4; ++j) {
      S[j] = (f32x4){0.f, 0.f, 0.f, 0.f};
      S[j] = __builtin_amdgcn_mfma_f32_16x16x32_bf16(aq0, kc[j][0], S[j], 0, 0, 0);
      S[j] = __builtin_amdgcn_mfma_f32_16x16x32_bf16(aq1, kc[j][1], S[j], 0, 0, 0);
    }

    // ---- online softmax (row q = g*4+e, values across cc-lanes x j) ----
    float p_[4][4];   // [j][e]
    #pragma unroll
    for (int e = 0; e < 4; ++e) {
      float mm = -3.0e38f;
      #pragma unroll
      for (int j = 0; j < 4; ++j) {
        float sv = S[j][e] * 0.125f;
        if (CAUSAL && cur == qb) {
          int ql = w * 16 + g * 4 + e, kl = j * 16 + cc;
          if (kl > ql) sv = -1e9f;
        }
        p_[j][e] = sv;
        mm = fmaxf(mm, sv);
      }
      mm = fmaxf(mm, __shfl_xor(mm, 1));
      mm = fmaxf(mm, __shfl_xor(mm, 2));
      mm = fmaxf(mm, __shfl_xor(mm, 4));
      mm = fmaxf(mm, __shfl_xor(mm, 8));
      float newm = fmaxf(m_[e], mm);
      float corr = __expf(m_[e] - newm);
      float rs = 0.f;
      #pragma unroll
      for (int j = 0; j < 4; ++j) {
        float p = __expf(p_[j][e] - newm);
        p_[j][e] = p;
        rs += p;
      }
      rs += __shfl_xor(rs, 1); rs += __shfl_xor(rs, 2);
      rs += __shfl_xor(rs, 4); rs += __shfl_xor(rs, 8);
      l_[e] = l_[e] * corr + rs;
      m_[e] = newm;
      #pragma unroll
      for (int j = 0; j < 4; ++j) accO[j][e] *= corr;
      int ql = g * 4 + e;
      #pragma unroll
      for (int j = 0; j < 4; ++j) {
        int kv = j * 16 + cc;
        int byt = ql * 128 + ((((kv >> 3) ^ (ql & 7))) << 4) + ((kv & 7) << 1);
        *(unsigned short*)(Pw + byt) = bfbits(p_[j][e]);
      }
    }

    // ---- PV: A-frags from per-wave P tile, B-frags from prefetched V ----
    #pragma unroll
    for (int s = 0; s < 2; ++s) {
      bf16x8 ap = *(const bf16x8*)(Pw + cc * 128 + (((s * 4 + g) ^ (cc & 7)) << 4));
      #pragma unroll
      for (int j = 0; j < 4; ++j)
        accO[j] = __builtin_amdgcn_mfma_f32_16x16x32_bf16(ap, vc[j][s], accO[j], 0, 0, 0);
    }

    if (!more) break;
    #pragma unroll
    for (int j = 0; j < 4; ++j) {
      kc[j][0] = kn[j][0]; kc[j][1] = kn[j][1];
      vc[j][0] = vn[j][0]; vc[j][1] = vn[j][1];
    }
    cur = nxt;
  }

  #pragma unroll
  for (int e = 0; e < 4; ++e) {
    float inv = 1.0f / fmaxf(l_[e], 1e-30f);
    int tok = b * S_LEN + strip * 16 + g * 4 + e;
    #pragma unroll
    for (int j = 0; j < 4; ++j)
      O[(size_t)tok * DIM + h * HDIM + j * 16 + cc] = __float2bfloat16(accO[j][e] * inv);
  }
}

extern "C" void kernel_launch(void* const* d_in, const int* in_sizes, int n_in,
                              void* d_out, int out_size, void* d_ws, size_t ws_size,
                              hipStream_t stream) {
  const float* q    = (const float*)d_in[0];
  const float* enc  = (const float*)d_in[1];
  const unsigned char* bbm = (const unsigned char*)d_in[2];
  const float* Wsrc[8] = {(const float*)d_in[3], (const float*)d_in[4],
                          (const float*)d_in[5], (const float*)d_in[6],
                          (const float*)d_in[7], (const float*)d_in[8],
                          (const float*)d_in[9], (const float*)d_in[10]};
  const float* ln_g = (const float*)d_in[11];
  const float* ln_b = (const float*)d_in[12];
  const float* W1   = (const float*)d_in[13];
  const float* b1   = (const float*)d_in[14];
  const float* W2   = (const float*)d_in[15];
  const float* b2   = (const float*)d_in[16];

  char* ws = (char*)d_ws;
  unsigned char* maskn = (unsigned char*)ws;
  const size_t WT1 = (size_t)DIM * DIM * 2;      // 1,179,648
  __hip_bfloat16* Wt[8];
  for (int i = 0; i < 8; ++i) Wt[i] = (__hip_bfloat16*)(ws + 4096 + i * WT1);
  __hip_bfloat16* W1t  = (__hip_bfloat16*)(ws + 9441280);
  __hip_bfloat16* W2t  = (__hip_bfloat16*)(ws + 14159872);
  __hip_bfloat16* Ebf  = (__hip_bfloat16*)(ws + 18878464);
  float*          X    = (float*)         (ws + 31461376);
  __hip_bfloat16* Abf  = (__hip_bfloat16*)(ws + 56627200);
  __hip_bfloat16* Bq   = (__hip_bfloat16*)(ws + 69210112);
  __hip_bfloat16* Bk   = (__hip_bfloat16*)(ws + 81793024);
  __hip_bfloat16* Vt   = (__hip_bfloat16*)(ws + 94375936);
  __hip_bfloat16* Cc   = (__hip_bfloat16*)(ws + 106958848);
  __hip_bfloat16* F    = Bq;   // [8192][3072] aliases Bq..Cc (dead in FFN phase)

  dim3 blk(256);
  dim3 gsq(12, 12), gw1(48, 12), gw2(12, 48);
  dim3 g768(6, 64), gff(24, 64);
  dim3 ga(1536);

  mask_norm_k<<<4, blk, 0, stream>>>(bbm, maskn);
  for (int i = 0; i < 8; ++i)
    tcast_k<<<gsq, blk, 0, stream>>>(Wsrc[i], Wt[i], DIM, DIM);
  tcast_k<<<gw1, blk, 0, stream>>>(W1, W1t, DIM, DFF_);
  tcast_k<<<gw2, blk, 0, stream>>>(W2, W2t, DFF_, DIM);
  castbf_k<<<3072, blk, 0, stream>>>(enc, Ebf, BTOK * DIM);

  // ---- self attention ----
  ln_k<<<BTOK, blk, 0, stream>>>(q, ln_g, ln_b, Abf);
  mgemm_k<true,false,false,false,false><<<g768, blk, 0, stream>>>(Abf, Wt[0], nullptr, nullptr, Bq, BTOK, DIM, DIM);
  mgemm_k<true,false,false,false,false><<<g768, blk, 0, stream>>>(Abf, Wt[1], nullptr, nullptr, Bk, BTOK, DIM, DIM);
  mgemm_k<true,false,false,false,true ><<<g768, blk, 0, stream>>>(Abf, Wt[2], nullptr, nullptr, Vt, BTOK, DIM, DIM);
  mattn_k<true><<<ga, blk, 0, stream>>>(Bq, Bk, Vt, Cc, maskn);
  mgemm_k<false,false,true,false,false><<<g768, blk, 0, stream>>>(Cc, Wt[3], nullptr, q, X, BTOK, DIM, DIM);

  // ---- cross attention (KV from raw encoder_out) ----
  ln_k<<<BTOK, blk, 0, stream>>>(X, ln_g, ln_b, Abf);
  mgemm_k<true,false,false,false,false><<<g768, blk, 0, stream>>>(Abf, Wt[4], nullptr, nullptr, Bq, BTOK, DIM, DIM);
  mgemm_k<true,false,false,false,false><<<g768, blk, 0, stream>>>(Ebf, Wt[5], nullptr, nullptr, Bk, BTOK, DIM, DIM);
  mgemm_k<true,false,false,false,true ><<<g768, blk, 0, stream>>>(Ebf, Wt[6], nullptr, nullptr, Vt, BTOK, DIM, DIM);
  mattn_k<false><<<ga, blk, 0, stream>>>(Bq, Bk, Vt, Cc, maskn);
  mgemm_k<false,false,true,false,false><<<g768, blk, 0, stream>>>(Cc, Wt[7], nullptr, X, X, BTOK, DIM, DIM);

  // ---- FFN ----
  ln_k<<<BTOK, blk, 0, stream>>>(X, ln_g, ln_b, Abf);
  mgemm_k<true,true,false,true,false><<<gff, blk, 0, stream>>>(Abf, W1t, b1, nullptr, F, BTOK, DFF_, DIM);
  mgemm_k<false,true,true,false,false><<<g768, blk, 0, stream>>>(F, W2t, b2, X, d_out, BTOK, DIM, DFF_);

  (void)in_sizes; (void)n_in; (void)out_size; (void)ws_size;
}

// Round 6
// 728.952 us; speedup vs baseline: 1.2289x; 1.1864x over previous
//
#include <hip/hip_runtime.h>
#include <hip/hip_bf16.h>

#define S_LEN 2048
#define DIM   768
#define NHEAD 12
#define HDIM  64
#define NBLK  32
#define BTOK  8192   // B * S
#define DFF_  3072

typedef __attribute__((ext_vector_type(8))) short bf16x8;
typedef __attribute__((ext_vector_type(4))) float f32x4;

__device__ __forceinline__ void glds16(const void* g, void* l) {
  __builtin_amdgcn_global_load_lds(
      (const __attribute__((address_space(1))) void*)g,
      (__attribute__((address_space(3))) void*)l, 16, 0, 0);
}

__device__ __forceinline__ unsigned int bfbits(float f) {
  __hip_bfloat16 t = __float2bfloat16(f);
  return (unsigned int)*(unsigned short*)&t;
}

// ---------------- bb_mask normalization (bool-byte or int32 layout) ---------
__global__ void mask_norm_k(const unsigned char* __restrict__ p,
                            unsigned char* __restrict__ out) {
  int i = blockIdx.x * 256 + threadIdx.x;
  if (i < NBLK * NBLK) {
    bool byteLayout = (p[1] != 0);   // m[0][1] always true
    out[i] = byteLayout ? (unsigned char)(p[i] != 0)
                        : (unsigned char)(((const int*)p)[i] != 0);
  }
}

// ---------------- layernorm: f32 in -> bf16 out, one block per row ----------
__device__ __forceinline__ float blockReduceSum256(float v) {
  v += __shfl_down(v, 32); v += __shfl_down(v, 16); v += __shfl_down(v, 8);
  v += __shfl_down(v, 4);  v += __shfl_down(v, 2);  v += __shfl_down(v, 1);
  __shared__ float sm[4];
  int w = threadIdx.x >> 6;
  __syncthreads();
  if ((threadIdx.x & 63) == 0) sm[w] = v;
  __syncthreads();
  return sm[0] + sm[1] + sm[2] + sm[3];
}

__global__ __launch_bounds__(256) void ln_k(const float* __restrict__ x,
                                            const float* __restrict__ g,
                                            const float* __restrict__ b,
                                            __hip_bfloat16* __restrict__ y) {
  size_t row = blockIdx.x;
  const float* xr = x + row * DIM;
  int t = threadIdx.x;
  float v0 = xr[t], v1 = xr[t + 256], v2 = xr[t + 512];
  float tot = blockReduceSum256(v0 + v1 + v2);
  float mu = tot * (1.0f / DIM);
  float d0 = v0 - mu, d1 = v1 - mu, d2 = v2 - mu;
  float var = blockReduceSum256(d0 * d0 + d1 * d1 + d2 * d2) * (1.0f / DIM);
  float rstd = rsqrtf(var + 1e-5f);
  __hip_bfloat16* yr = y + row * DIM;
  yr[t]       = __float2bfloat16(d0 * rstd * g[t]       + b[t]);
  yr[t + 256] = __float2bfloat16(d1 * rstd * g[t + 256] + b[t + 256]);
  yr[t + 512] = __float2bfloat16(d2 * rstd * g[t + 512] + b[t + 512]);
}

// ---------------- elementwise f32 -> bf16 cast ------------------------------
__global__ __launch_bounds__(256) void castbf_k(const float* __restrict__ x,
                                                __hip_bfloat16* __restrict__ y,
                                                int n) {
  int i = (blockIdx.x * 256 + threadIdx.x) * 8;
  if (i < n) {
    float4 v0 = *(const float4*)(x + i);
    float4 v1 = *(const float4*)(x + i + 4);
    union { bf16x8 v; unsigned short u[8]; } pk;
    pk.u[0] = bfbits(v0.x); pk.u[1] = bfbits(v0.y);
    pk.u[2] = bfbits(v0.z); pk.u[3] = bfbits(v0.w);
    pk.u[4] = bfbits(v1.x); pk.u[5] = bfbits(v1.y);
    pk.u[6] = bfbits(v1.z); pk.u[7] = bfbits(v1.w);
    *(bf16x8*)((unsigned short*)y + i) = pk.v;
  }
}

// ---------------- weight transpose+cast: W[R][C] f32 -> Wt[C][R] bf16 -------
__global__ __launch_bounds__(256) void tcast_k(const float* __restrict__ W,
                                               __hip_bfloat16* __restrict__ Wt,
                                               int R, int C) {
  __shared__ float T[64][65];
  int r0 = blockIdx.y * 64, c0 = blockIdx.x * 64;
  int t = threadIdx.x;
  int r = t >> 2, cg = (t & 3) * 16;
  #pragma unroll
  for (int ii = 0; ii < 16; ii += 4) {
    float4 v = *(const float4*)(W + (size_t)(r0 + r) * C + c0 + cg + ii);
    T[r][cg + ii + 0] = v.x; T[r][cg + ii + 1] = v.y;
    T[r][cg + ii + 2] = v.z; T[r][cg + ii + 3] = v.w;
  }
  __syncthreads();
  int oc = t >> 2, og = (t & 3) * 16;
  union { bf16x8 v; unsigned short u[8]; } p0, p1;
  #pragma unroll
  for (int ii = 0; ii < 8; ++ii) p0.u[ii] = bfbits(T[og + ii][oc]);
  #pragma unroll
  for (int ii = 0; ii < 8; ++ii) p1.u[ii] = bfbits(T[og + 8 + ii][oc]);
  unsigned short* dst = (unsigned short*)Wt + (size_t)(c0 + oc) * R + r0 + og;
  *(bf16x8*)dst = p0.v;
  *(bf16x8*)(dst + 8) = p1.v;
}

// ---------------- bf16 MFMA GEMM: C = A[M,K] @ Bt[N,K]^T --------------------
// SPLIT=0: single dest o1 (bf16 or f32). SPLIT=1: QKV (cols 0-767 -> o1 bf16,
// 768-1535 -> o2 bf16, 1536-2303 -> o3 = Vt[b][d][s] transposed). SPLIT=2:
// KV (0-767 -> o1, 768-1535 -> o2 transposed). Dest row stride 768 for splits.
template<bool BF16OUT, bool HASBIAS, bool HASRES, bool RELU, int SPLIT>
__global__ __launch_bounds__(256) void mgemm_k(
    const __hip_bfloat16* __restrict__ A,   // [M][K] bf16
    const __hip_bfloat16* __restrict__ Bt,  // [N][K] bf16
    const float* __restrict__ bias,
    const float* __restrict__ resid,        // f32 [M][N]
    void* __restrict__ o1, void* __restrict__ o2, void* __restrict__ o3,
    int M, int N, int K) {
  __shared__ char Asl[128 * 128];   // 128 rows x 64 bf16
  __shared__ char Bsl[128 * 128];
  int tid = threadIdx.x, w = tid >> 6, lane = tid & 63;
  int g = lane >> 4, cc = lane & 15;
  int wr = w >> 1, wc = w & 1;
  int m0 = blockIdx.y * 128, n0 = blockIdx.x * 128;

  f32x4 acc[4][4];
  #pragma unroll
  for (int i = 0; i < 4; ++i)
    #pragma unroll
    for (int j = 0; j < 4; ++j) acc[i][j] = (f32x4){0.f, 0.f, 0.f, 0.f};

  for (int k0 = 0; k0 < K; k0 += 64) {
    __syncthreads();
    #pragma unroll
    for (int ii = 0; ii < 4; ++ii) {
      int chunk = ii * 256 + w * 64 + lane;
      int row = chunk >> 3, hh = chunk & 7;
      int koff = k0 + ((hh ^ (row & 7)) << 3);
      glds16(A  + (size_t)(m0 + row) * K + koff, Asl + (ii * 256 + w * 64) * 16);
      glds16(Bt + (size_t)(n0 + row) * K + koff, Bsl + (ii * 256 + w * 64) * 16);
    }
    __syncthreads();
    bf16x8 a[4][2], b[4][2];
    #pragma unroll
    for (int i = 0; i < 4; ++i)
      #pragma unroll
      for (int s = 0; s < 2; ++s) {
        int row = wr * 64 + i * 16 + cc;
        a[i][s] = *(const bf16x8*)(Asl + row * 128 + (((s * 4 + g) ^ (cc & 7)) << 4));
      }
    #pragma unroll
    for (int j = 0; j < 4; ++j)
      #pragma unroll
      for (int s = 0; s < 2; ++s) {
        int row = wc * 64 + j * 16 + cc;
        b[j][s] = *(const bf16x8*)(Bsl + row * 128 + (((s * 4 + g) ^ (cc & 7)) << 4));
      }
    #pragma unroll
    for (int i = 0; i < 4; ++i)
      #pragma unroll
      for (int j = 0; j < 4; ++j)
        #pragma unroll
        for (int s = 0; s < 2; ++s)
          acc[i][j] = __builtin_amdgcn_mfma_f32_16x16x32_bf16(a[i][s], b[j][s], acc[i][j], 0, 0, 0);
  }
  int range = n0 / 768;           // block-uniform (split dests)
  #pragma unroll
  for (int i = 0; i < 4; ++i)
    #pragma unroll
    for (int j = 0; j < 4; ++j)
      #pragma unroll
      for (int e = 0; e < 4; ++e) {
        int r   = m0 + wr * 64 + i * 16 + g * 4 + e;
        int col = n0 + wc * 64 + j * 16 + cc;
        float v = acc[i][j][e];
        if (HASBIAS) v += bias[col];
        if (HASRES)  v += resid[(size_t)r * N + col];
        if (RELU)    v = fmaxf(v, 0.f);
        if (SPLIT == 0) {
          if (BF16OUT) ((__hip_bfloat16*)o1)[(size_t)r * N + col] = __float2bfloat16(v);
          else         ((float*)o1)[(size_t)r * N + col] = v;
        } else {
          int cl = col - range * 768;
          void* dst; bool trans;
          if (SPLIT == 1) { dst = range == 0 ? o1 : (range == 1 ? o2 : o3); trans = (range == 2); }
          else            { dst = range == 0 ? o1 : o2;                      trans = (range == 1); }
          if (trans) {
            int bb = r >> 11, s = r & 2047;   // Vt[b][cl][s]
            ((__hip_bfloat16*)dst)[(size_t)bb * DIM * S_LEN + (size_t)cl * S_LEN + s] = __float2bfloat16(v);
          } else {
            ((__hip_bfloat16*)dst)[(size_t)r * 768 + cl] = __float2bfloat16(v);
          }
        }
      }
}

// ---------------- block-sparse MFMA flash attention, swapped-QK -------------
// Grid 6144 x 64 thr (one wave per 16-row q-strip). XCD-chunked bijective
// swizzle; heavy-qb-first order inside each chunk. Swapped QK^T (mfma(K,Q))
// puts a full q-row (q=cc) in each lane: k = j*16+g*4+e -> softmax max is
// register-local; l_ kept lane-partial (reduced across g once at end).
// Defer-max (THR=8): steady state has ZERO cross-lane ops per kb-step.
// P written as 4x ds_write_b64 (k-contig), read back as PV A-frags (b128).
template<bool CAUSAL>
__global__ __launch_bounds__(64) void mattn_k(
    const __hip_bfloat16* __restrict__ Qg,   // [B*S][768]
    const __hip_bfloat16* __restrict__ Kg,   // [B*S][768]
    const __hip_bfloat16* __restrict__ Vtg,  // [B][768][2048]
    __hip_bfloat16* __restrict__ O,          // [B*S][768]
    const unsigned char* __restrict__ mask) {
  __shared__ char Ps[2048];
  int lin = blockIdx.x;
  int slot = (lin & 7) * 768 + (lin >> 3);   // bijective: 6144 = 8 * 768
  int pair = slot >> 7, sl = slot & 127;
  int rawqb = sl >> 2, w = sl & 3;
  int qb = CAUSAL ? (31 - rawqb)
                  : ((rawqb & 1) ? (31 - (rawqb >> 1)) : (rawqb >> 1));
  int h = pair % NHEAD, b = pair / NHEAD;
  int lane = threadIdx.x;
  int g = lane >> 4, cc = lane & 15;
  int strip = qb * 4 + w;
  const unsigned short* Qp = (const unsigned short*)Qg;
  const unsigned short* Kp = (const unsigned short*)Kg;
  const unsigned short* Vp = (const unsigned short*)Vtg;

  // Q fragments (B-operand of swapped QK): col q=cc, k(d)-contig at g*8
  bf16x8 aq0, aq1;
  size_t qrow = ((size_t)b * S_LEN + strip * 16 + cc) * DIM + h * HDIM;
  aq0 = *(const bf16x8*)(Qp + qrow + g * 8);
  aq1 = *(const bf16x8*)(Qp + qrow + (4 + g) * 8);

  float m_ = -1e30f, l_ = 0.f;    // stats of q-row cc (l_ = lane partial)
  f32x4 accO[4];
  #pragma unroll
  for (int j = 0; j < 4; ++j) accO[j] = (f32x4){0.f, 0.f, 0.f, 0.f};

  const unsigned char* mrow = mask + qb * NBLK;
  int kbEnd = CAUSAL ? (qb + 1) : NBLK;

  for (int kb = 0; kb < kbEnd; ++kb) {
    if (!mrow[kb]) continue;

    // K frags (A-operand rows k=j*16+cc) and V frags (PV B-operand)
    bf16x8 kc[4][2], vc[4][2];
    #pragma unroll
    for (int j = 0; j < 4; ++j) {
      size_t kro = ((size_t)b * S_LEN + kb * 64 + j * 16 + cc) * DIM + h * HDIM + g * 8;
      kc[j][0] = *(const bf16x8*)(Kp + kro);
      kc[j][1] = *(const bf16x8*)(Kp + kro + 32);
      size_t vro = ((size_t)b * DIM + h * HDIM + j * 16 + cc) * S_LEN + kb * 64 + g * 8;
      vc[j][0] = *(const bf16x8*)(Vp + vro);
      vc[j][1] = *(const bf16x8*)(Vp + vro + 32);
    }

    // ---- QK^T swapped: S[j] holds S[k = j*16+g*4+e][q = cc] ----
    f32x4 S[4];
    #pragma unroll
    for (int j = 0; j < 4; ++j) {
      S[j] = (f32x4){0.f, 0.f, 0.f, 0.f};
      S[j] = __builtin_amdgcn_mfma_f32_16x16x32_bf16(kc[j][0], aq0, S[j], 0, 0, 0);
      S[j] = __builtin_amdgcn_mfma_f32_16x16x32_bf16(kc[j][1], aq1, S[j], 0, 0, 0);
    }

    // ---- scale + causal mask + register-local row max ----
    float p[4][4];
    float mmL = -1e30f;
    #pragma unroll
    for (int j = 0; j < 4; ++j)
      #pragma unroll
      for (int e = 0; e < 4; ++e) {
        float sv = S[j][e] * 0.125f;
        if (CAUSAL && kb == qb) {
          int kwi = j * 16 + g * 4 + e, qwi = w * 16 + cc;
          if (kwi > qwi) sv = -1e9f;
        }
        p[j][e] = sv;
        mmL = fmaxf(mmL, sv);
      }

    // ---- defer-max: slow path only when some row's max grew > THR ----
    if (!__all(mmL <= m_ + 8.0f)) {
      float mm = fmaxf(mmL, __shfl_xor(mmL, 16));
      mm = fmaxf(mm, __shfl_xor(mm, 32));          // row max across g-lanes
      float newm = fmaxf(m_, mm);
      float corr = __expf(m_ - newm);
      m_ = newm;
      l_ *= corr;
      #pragma unroll
      for (int e = 0; e < 4; ++e) {                // corr of accO's row g*4+e
        int src = (lane & 48) | (g * 4 + e);
        float ce = __shfl(corr, src);
        #pragma unroll
        for (int j = 0; j < 4; ++j) accO[j][e] *= ce;
      }
    }

    // ---- exp + lane-partial sum ----
    float rs = 0.f;
    #pragma unroll
    for (int j = 0; j < 4; ++j)
      #pragma unroll
      for (int e = 0; e < 4; ++e) {
        float pe = __expf(p[j][e] - m_);
        p[j][e] = pe;
        rs += pe;
      }
    l_ += rs;

    // ---- pack P -> LDS (row cc, kv0 = j*16+g*4, b64 each) ----
    #pragma unroll
    for (int j = 0; j < 4; ++j) {
      unsigned int lo = bfbits(p[j][0]) | (bfbits(p[j][1]) << 16);
      unsigned int hi = bfbits(p[j][2]) | (bfbits(p[j][3]) << 16);
      int kv0 = j * 16 + g * 4;
      int byt = cc * 128 + (((kv0 >> 3) ^ (cc & 7)) << 4) + ((kv0 & 7) << 1);
      *(unsigned long long*)(Ps + byt) =
          (unsigned long long)lo | ((unsigned long long)hi << 32);
    }

    // ---- PV: A = P (row q=cc, k-contig), B = V frags ----
    #pragma unroll
    for (int s = 0; s < 2; ++s) {
      bf16x8 ap = *(const bf16x8*)(Ps + cc * 128 + (((s * 4 + g) ^ (cc & 7)) << 4));
      #pragma unroll
      for (int j = 0; j < 4; ++j)
        accO[j] = __builtin_amdgcn_mfma_f32_16x16x32_bf16(ap, vc[j][s], accO[j], 0, 0, 0);
    }
  }

  // ---- finalize: row sum across g-lanes, then map to accO rows ----
  float lt = l_ + __shfl_xor(l_, 16);
  lt += __shfl_xor(lt, 32);                        // row-cc total, g-uniform
  #pragma unroll
  for (int e = 0; e < 4; ++e) {
    int src = (lane & 48) | (g * 4 + e);
    float le = __shfl(lt, src);
    float inv = 1.0f / fmaxf(le, 1e-30f);
    int tok = b * S_LEN + strip * 16 + g * 4 + e;
    #pragma unroll
    for (int j = 0; j < 4; ++j)
      O[(size_t)tok * DIM + h * HDIM + j * 16 + cc] = __float2bfloat16(accO[j][e] * inv);
  }
}

extern "C" void kernel_launch(void* const* d_in, const int* in_sizes, int n_in,
                              void* d_out, int out_size, void* d_ws, size_t ws_size,
                              hipStream_t stream) {
  const float* q    = (const float*)d_in[0];
  const float* enc  = (const float*)d_in[1];
  const unsigned char* bbm = (const unsigned char*)d_in[2];
  const float* Wsrc[8] = {(const float*)d_in[3], (const float*)d_in[4],
                          (const float*)d_in[5], (const float*)d_in[6],
                          (const float*)d_in[7], (const float*)d_in[8],
                          (const float*)d_in[9], (const float*)d_in[10]};
  const float* ln_g = (const float*)d_in[11];
  const float* ln_b = (const float*)d_in[12];
  const float* W1   = (const float*)d_in[13];
  const float* b1   = (const float*)d_in[14];
  const float* W2   = (const float*)d_in[15];
  const float* b2   = (const float*)d_in[16];

  char* ws = (char*)d_ws;
  unsigned char* maskn = (unsigned char*)ws;
  const size_t WT1 = (size_t)DIM * DIM * 2;      // 1,179,648
  __hip_bfloat16* Wt[8];
  for (int i = 0; i < 8; ++i) Wt[i] = (__hip_bfloat16*)(ws + 4096 + i * WT1);
  __hip_bfloat16* W1t  = (__hip_bfloat16*)(ws + 9441280);
  __hip_bfloat16* W2t  = (__hip_bfloat16*)(ws + 14159872);
  __hip_bfloat16* Ebf  = (__hip_bfloat16*)(ws + 18878464);
  float*          X    = (float*)         (ws + 31461376);
  __hip_bfloat16* Abf  = (__hip_bfloat16*)(ws + 56627200);
  __hip_bfloat16* Bq   = (__hip_bfloat16*)(ws + 69210112);
  __hip_bfloat16* Bk   = (__hip_bfloat16*)(ws + 81793024);
  __hip_bfloat16* Vt   = (__hip_bfloat16*)(ws + 94375936);
  __hip_bfloat16* Cc   = (__hip_bfloat16*)(ws + 106958848);
  __hip_bfloat16* F    = Bq;   // [8192][3072] aliases Bq..Cc (dead in FFN phase)

  dim3 blk(256);
  dim3 gsq(12, 12), gw1(48, 12), gw2(12, 48);
  dim3 g768(6, 64), gqkv(18, 64), gkv(12, 64), gff(24, 64);
  dim3 ga(6144);
  dim3 wv(64);

  mask_norm_k<<<4, blk, 0, stream>>>(bbm, maskn);
  for (int i = 0; i < 8; ++i)
    tcast_k<<<gsq, blk, 0, stream>>>(Wsrc[i], Wt[i], DIM, DIM);
  tcast_k<<<gw1, blk, 0, stream>>>(W1, W1t, DIM, DFF_);
  tcast_k<<<gw2, blk, 0, stream>>>(W2, W2t, DFF_, DIM);
  castbf_k<<<3072, blk, 0, stream>>>(enc, Ebf, BTOK * DIM);

  // ---- self attention: fused QKV projection (Wt[0..2] contiguous) ----
  ln_k<<<BTOK, blk, 0, stream>>>(q, ln_g, ln_b, Abf);
  mgemm_k<true,false,false,false,1><<<gqkv, blk, 0, stream>>>(
      Abf, Wt[0], nullptr, nullptr, Bq, Bk, Vt, BTOK, 2304, DIM);
  mattn_k<true><<<ga, wv, 0, stream>>>(Bq, Bk, Vt, Cc, maskn);
  mgemm_k<false,false,true,false,0><<<g768, blk, 0, stream>>>(
      Cc, Wt[3], nullptr, q, X, nullptr, nullptr, BTOK, DIM, DIM);

  // ---- cross attention: Q proj + fused KV (Wt[5..6] contiguous) ----
  ln_k<<<BTOK, blk, 0, stream>>>(X, ln_g, ln_b, Abf);
  mgemm_k<true,false,false,false,0><<<g768, blk, 0, stream>>>(
      Abf, Wt[4], nullptr, nullptr, Bq, nullptr, nullptr, BTOK, DIM, DIM);
  mgemm_k<true,false,false,false,2><<<gkv, blk, 0, stream>>>(
      Ebf, Wt[5], nullptr, nullptr, Bk, Vt, nullptr, BTOK, 1536, DIM);
  mattn_k<false><<<ga, wv, 0, stream>>>(Bq, Bk, Vt, Cc, maskn);
  mgemm_k<false,false,true,false,0><<<g768, blk, 0, stream>>>(
      Cc, Wt[7], nullptr, X, X, nullptr, nullptr, BTOK, DIM, DIM);

  // ---- FFN ----
  ln_k<<<BTOK, blk, 0, stream>>>(X, ln_g, ln_b, Abf);
  mgemm_k<true,true,false,true,0><<<gff, blk, 0, stream>>>(
      Abf, W1t, b1, nullptr, F, nullptr, nullptr, BTOK, DFF_, DIM);
  mgemm_k<false,true,true,false,0><<<g768, blk, 0, stream>>>(
      F, W2t, b2, X, d_out, nullptr, nullptr, BTOK, DIM, DFF_);

  (void)in_sizes; (void)n_in; (void)out_size; (void)ws_size;
}